// Round 1
// baseline (183.951 us; speedup 1.0000x reference)
//
#include <hip/hip_runtime.h>
#include <stdint.h>

// Problem constants
#define B_    2
#define NQ    2048
#define NKV   2048
#define D_    512
#define H_    8
#define HD    64
#define MROWS 4096   // B_*NQ == B_*NKV

typedef unsigned short u16;
typedef __attribute__((ext_vector_type(4))) unsigned short u16x4;
typedef __attribute__((ext_vector_type(8))) unsigned short u16x8;
typedef __attribute__((ext_vector_type(8))) __bf16 bf16x8;
typedef __attribute__((ext_vector_type(4))) float f32x4;

__device__ __forceinline__ u16 f2bf(float f) {
  union { float f; unsigned int u; } v; v.f = f;
  unsigned int u = v.u;
  unsigned int r = (u + 0x7FFFu + ((u >> 16) & 1u)) >> 16;  // RNE
  return (u16)r;
}

__device__ __forceinline__ f32x4 mfma16(u16x8 a, u16x8 b, f32x4 c) {
  return __builtin_amdgcn_mfma_f32_16x16x32_bf16(
      __builtin_bit_cast(bf16x8, a), __builtin_bit_cast(bf16x8, b), c, 0, 0, 0);
}

// ---------------------------------------------------------------------------
// Kernel 1: cast inputs to bf16; transpose weights to (N x K) bf16 so that
// GEMM B-fragments are contiguous 16B loads.
// ---------------------------------------------------------------------------
__global__ __launch_bounds__(256) void cast_kernel(
    const float* __restrict__ q, const float* __restrict__ kv,
    const float* __restrict__ Wq, const float* __restrict__ Wk,
    const float* __restrict__ Wv,
    u16* __restrict__ qb, u16* __restrict__ kvb,
    u16* __restrict__ wqt, u16* __restrict__ wkt, u16* __restrict__ wvt) {
  int i = blockIdx.x * 256 + threadIdx.x;
  const int NVEC = (MROWS * D_) / 4;  // 524288 float4 casts
  if (i < NVEC) {
    float4 a = ((const float4*)q)[i];
    float4 b = ((const float4*)kv)[i];
    u16x4 ua = { f2bf(a.x), f2bf(a.y), f2bf(a.z), f2bf(a.w) };
    u16x4 ub = { f2bf(b.x), f2bf(b.y), f2bf(b.z), f2bf(b.w) };
    ((u16x4*)qb)[i]  = ua;
    ((u16x4*)kvb)[i] = ub;
  } else {
    int t = i - NVEC;            // 0 .. 3*512*512-1
    if (t < 3 * D_ * D_) {
      int w = t >> 18;           // which weight
      int r = t & (D_ * D_ - 1); // output index: n*512 + k
      int n = r >> 9, k = r & 511;
      const float* W = (w == 0) ? Wq : (w == 1) ? Wk : Wv;
      u16* WT = (w == 0) ? wqt : (w == 1) ? wkt : wvt;
      WT[r] = f2bf(W[k * D_ + n]);  // WT[n][k] = W[k][n]
    }
  }
}

// ---------------------------------------------------------------------------
// Kernel 2: bf16 GEMM  Out(M x 512) = A(M x 512) * W + bias, W given as WT
// (512 x 512, row n holds column n of W). 128x128 tile / block, 4 waves in
// 2x2, each wave a 64x64 sub-tile of 4x4 16x16x32 MFMA fragments.
// Fragments loaded directly from global (16B/lane, contiguous).
// ---------------------------------------------------------------------------
__global__ __launch_bounds__(256) void gemm_proj(
    const u16* __restrict__ A, const u16* __restrict__ WT,
    const float* __restrict__ bias, u16* __restrict__ Out) {
  int lane = threadIdx.x & 63, w = threadIdx.x >> 6;
  int wr = w >> 1, wc = w & 1;
  int cl = lane & 15, g = lane >> 4;
  int row0 = blockIdx.x * 128, col0 = blockIdx.y * 128;

  f32x4 acc[4][4] = {};
  const u16* Abase = A  + (size_t)(row0 + wr * 64 + cl) * D_ + g * 8;
  const u16* Bbase = WT + (size_t)(col0 + wc * 64 + cl) * D_ + g * 8;

  for (int k0 = 0; k0 < D_; k0 += 32) {
    u16x8 af[4], bf[4];
#pragma unroll
    for (int i = 0; i < 4; ++i)
      af[i] = *(const u16x8*)(Abase + (size_t)i * 16 * D_ + k0);
#pragma unroll
    for (int j = 0; j < 4; ++j)
      bf[j] = *(const u16x8*)(Bbase + (size_t)j * 16 * D_ + k0);
#pragma unroll
    for (int i = 0; i < 4; ++i)
#pragma unroll
      for (int j = 0; j < 4; ++j)
        acc[i][j] = mfma16(af[i], bf[j], acc[i][j]);
  }

  // Epilogue: C/D layout col = lane&15, row = (lane>>4)*4 + reg
#pragma unroll
  for (int j = 0; j < 4; ++j) {
    int col = col0 + wc * 64 + j * 16 + cl;
    float bv = bias[col];
#pragma unroll
    for (int i = 0; i < 4; ++i) {
      int rowb = row0 + wr * 64 + i * 16 + g * 4;
#pragma unroll
      for (int r = 0; r < 4; ++r)
        Out[(size_t)(rowb + r) * D_ + col] = f2bf(acc[i][j][r] + bv);
    }
  }
}

// ---------------------------------------------------------------------------
// Kernel 3: flash attention per (b, h). Q-tile = 64 rows / block (4 waves x
// 16 rows). KV tiles of 64 keys. Masked (query-half) keys skipped entirely:
// expf(-1e4) == 0 in f32, so softmax denominator is unchanged vs reference.
// ---------------------------------------------------------------------------
__global__ __launch_bounds__(256) void attn_kernel(
    const u16* __restrict__ Q, const u16* __restrict__ K,
    const u16* __restrict__ V, float* __restrict__ ctx) {
  __shared__ u16 Vt[64][72];  // V transposed: [hd][key], +8 pad -> 2-way max
  __shared__ u16 Pl[64][72];  // P: [q_row_in_tile][key], same pad

  int lane = threadIdx.x & 63, w = threadIdx.x >> 6;
  int cl = lane & 15, g = lane >> 4;
  int q0 = blockIdx.x * 64, h = blockIdx.y, b = blockIdx.z;

  // Hoist Q fragments (wave w owns q-rows q0 + w*16 .. +15)
  const u16* Qb = Q + ((size_t)(b * NQ + q0 + w * 16 + cl)) * D_ + h * HD + g * 8;
  u16x8 qf0 = *(const u16x8*)Qb;
  u16x8 qf1 = *(const u16x8*)(Qb + 32);

  f32x4 o[4] = {};
  float m[4], lsum[4];
#pragma unroll
  for (int r = 0; r < 4; ++r) { m[r] = -1e30f; lsum[r] = 0.f; }

  const u16* Kb = K + (size_t)b * NKV * D_ + h * HD;
  const u16* Vb = V + (size_t)b * NKV * D_ + h * HD;

  for (int t = 0; t < NKV / 64; ++t) {
    int k0 = t * 64;
    __syncthreads();  // previous PV reads of Vt done before overwrite
    for (int s2 = threadIdx.x; s2 < 512; s2 += 256) {
      int key = s2 >> 3, hb = s2 & 7;
      u16x8 vv = *(const u16x8*)(Vb + (size_t)(k0 + key) * D_ + hb * 8);
#pragma unroll
      for (int e = 0; e < 8; ++e) Vt[hb * 8 + e][key] = vv[e];
    }
    __syncthreads();

    // S = Q K^T (A-frag = Q rows, B-frag = K rows, both contiguous 16B)
    f32x4 sa[4] = {};
    const u16* Kt = Kb + (size_t)(k0 + cl) * D_ + g * 8;
#pragma unroll
    for (int kk = 0; kk < 2; ++kk) {
      u16x8 qf = kk ? qf1 : qf0;
#pragma unroll
      for (int j = 0; j < 4; ++j) {
        u16x8 kf = *(const u16x8*)(Kt + (size_t)j * 16 * D_ + kk * 32);
        sa[j] = mfma16(qf, kf, sa[j]);
      }
    }
#pragma unroll
    for (int j = 0; j < 4; ++j)
#pragma unroll
      for (int r = 0; r < 4; ++r) sa[j][r] *= 0.125f;  // 1/sqrt(HD)

    // Online softmax. Row r_global = q0 + w*16 + g*4 + r, spread over the
    // 16 lanes sharing g and the 4 column fragments j.
    float p[4][4], al[4];
#pragma unroll
    for (int r = 0; r < 4; ++r) {
      float mx = fmaxf(fmaxf(sa[0][r], sa[1][r]), fmaxf(sa[2][r], sa[3][r]));
#pragma unroll
      for (int d = 1; d < 16; d <<= 1) mx = fmaxf(mx, __shfl_xor(mx, d, 64));
      float mn = fmaxf(m[r], mx);
      al[r] = __expf(m[r] - mn);
      float sum = 0.f;
#pragma unroll
      for (int j = 0; j < 4; ++j) { p[j][r] = __expf(sa[j][r] - mn); sum += p[j][r]; }
#pragma unroll
      for (int d = 1; d < 16; d <<= 1) sum += __shfl_xor(sum, d, 64);
      lsum[r] = lsum[r] * al[r] + sum;
      m[r] = mn;
    }
#pragma unroll
    for (int j = 0; j < 4; ++j)
#pragma unroll
      for (int r = 0; r < 4; ++r) o[j][r] *= al[r];

    // P -> LDS (same-wave write->read; DS ops within a wave are ordered)
#pragma unroll
    for (int j = 0; j < 4; ++j)
#pragma unroll
      for (int r = 0; r < 4; ++r)
        Pl[w * 16 + g * 4 + r][j * 16 + cl] = f2bf(p[j][r]);

    // O += P * V
#pragma unroll
    for (int kk = 0; kk < 2; ++kk) {
      u16x8 pa = *(const u16x8*)&Pl[w * 16 + cl][kk * 32 + g * 8];
#pragma unroll
      for (int j = 0; j < 4; ++j) {
        u16x8 vb2 = *(const u16x8*)&Vt[j * 16 + cl][kk * 32 + g * 8];
        o[j] = mfma16(pa, vb2, o[j]);
      }
    }
  }

#pragma unroll
  for (int r = 0; r < 4; ++r) lsum[r] = 1.f / lsum[r];
#pragma unroll
  for (int j = 0; j < 4; ++j)
#pragma unroll
    for (int r = 0; r < 4; ++r)
      ctx[(size_t)(b * NQ + q0 + w * 16 + g * 4 + r) * D_ + h * HD + j * 16 + cl]
          = o[j][r] * lsum[r];
}

// ---------------------------------------------------------------------------
// Kernel 4: resid = query + ctx; LayerNorm(resid) * gamma + beta.
// One wave per row of 512.
// ---------------------------------------------------------------------------
__global__ __launch_bounds__(64) void ln_kernel(
    const float* __restrict__ query, const float* __restrict__ ctx,
    const float* __restrict__ gamma, const float* __restrict__ beta,
    float* __restrict__ out) {
  int row = blockIdx.x, lane = threadIdx.x;
  size_t base = (size_t)row * D_;
  const float4* q4 = (const float4*)(query + base);
  const float4* c4 = (const float4*)(ctx + base);
  float4 a0 = q4[lane * 2], a1 = q4[lane * 2 + 1];
  float4 b0 = c4[lane * 2], b1 = c4[lane * 2 + 1];
  float x[8] = { a0.x + b0.x, a0.y + b0.y, a0.z + b0.z, a0.w + b0.w,
                 a1.x + b1.x, a1.y + b1.y, a1.z + b1.z, a1.w + b1.w };
  float sum = 0.f, sq = 0.f;
#pragma unroll
  for (int e = 0; e < 8; ++e) { sum += x[e]; sq += x[e] * x[e]; }
#pragma unroll
  for (int d = 1; d < 64; d <<= 1) {
    sum += __shfl_xor(sum, d, 64);
    sq  += __shfl_xor(sq,  d, 64);
  }
  float mean = sum * (1.f / D_);
  float var  = sq * (1.f / D_) - mean * mean;
  float rstd = rsqrtf(var + 1e-5f);
  const float4* g4  = (const float4*)gamma;
  const float4* be4 = (const float4*)beta;
  float4 g0 = g4[lane * 2], g1 = g4[lane * 2 + 1];
  float4 e0 = be4[lane * 2], e1 = be4[lane * 2 + 1];
  float4 o0, o1;
  o0.x = (x[0] - mean) * rstd * g0.x + e0.x;
  o0.y = (x[1] - mean) * rstd * g0.y + e0.y;
  o0.z = (x[2] - mean) * rstd * g0.z + e0.z;
  o0.w = (x[3] - mean) * rstd * g0.w + e0.w;
  o1.x = (x[4] - mean) * rstd * g1.x + e1.x;
  o1.y = (x[5] - mean) * rstd * g1.y + e1.y;
  o1.z = (x[6] - mean) * rstd * g1.z + e1.z;
  o1.w = (x[7] - mean) * rstd * g1.w + e1.w;
  ((float4*)(out + base))[lane * 2]     = o0;
  ((float4*)(out + base))[lane * 2 + 1] = o1;
}

// ---------------------------------------------------------------------------
// Workspace layout (bytes):
//   0         qb   : query bf16           4 MB
//   4194304   kvb  : key_value bf16       4 MB
//   8388608   wqt  : Wq^T bf16            0.5 MB
//   8912896   wkt  : Wk^T bf16            0.5 MB
//   9437184   wvt  : Wv^T bf16            0.5 MB
//   9961472   Qp   : Q proj bf16          4 MB
//   14155776  Kp   : K proj bf16          4 MB
//   18350080  Vp   : V proj bf16          4 MB
//   22544384  ctx  : attention out f32    8 MB
//   total ~29.5 MB
// ---------------------------------------------------------------------------
extern "C" void kernel_launch(void* const* d_in, const int* in_sizes, int n_in,
                              void* d_out, int out_size, void* d_ws, size_t ws_size,
                              hipStream_t stream) {
  const float* query     = (const float*)d_in[0];
  const float* key_value = (const float*)d_in[1];
  const float* Wq = (const float*)d_in[2];
  const float* bq = (const float*)d_in[3];
  const float* Wk = (const float*)d_in[4];
  const float* bk = (const float*)d_in[5];
  const float* Wv = (const float*)d_in[6];
  const float* bv = (const float*)d_in[7];
  const float* gamma = (const float*)d_in[8];
  const float* beta  = (const float*)d_in[9];
  float* out = (float*)d_out;

  char* ws = (char*)d_ws;
  u16* qb   = (u16*)(ws + 0);
  u16* kvb  = (u16*)(ws + 4194304);
  u16* wqt  = (u16*)(ws + 8388608);
  u16* wkt  = (u16*)(ws + 8912896);
  u16* wvt  = (u16*)(ws + 9437184);
  u16* Qp   = (u16*)(ws + 9961472);
  u16* Kp   = (u16*)(ws + 14155776);
  u16* Vp   = (u16*)(ws + 18350080);
  float* ctxp = (float*)(ws + 22544384);

  cast_kernel<<<5120, 256, 0, stream>>>(query, key_value, Wq, Wk, Wv,
                                        qb, kvb, wqt, wkt, wvt);
  dim3 gg(MROWS / 128, D_ / 128);
  gemm_proj<<<gg, 256, 0, stream>>>(qb,  wqt, bq, Qp);
  gemm_proj<<<gg, 256, 0, stream>>>(kvb, wkt, bk, Kp);
  gemm_proj<<<gg, 256, 0, stream>>>(kvb, wvt, bv, Vp);
  dim3 ga(NQ / 64, H_, B_);
  attn_kernel<<<ga, 256, 0, stream>>>(Qp, Kp, Vp, ctxp);
  ln_kernel<<<MROWS, 64, 0, stream>>>(query, ctxp, gamma, beta, out);
}

// Round 2
// 159.365 us; speedup vs baseline: 1.1543x; 1.1543x over previous
//
#include <hip/hip_runtime.h>
#include <stdint.h>

// Problem constants
#define B_     2
#define NQ     2048
#define NKV    2048
#define D_     512
#define H_     8
#define HD     64
#define MROWS  4096   // B_*NQ == B_*NKV
#define NSPLIT 4
#define SKEYS  (NKV / NSPLIT)   // 512 keys per split

typedef unsigned short u16;
typedef __attribute__((ext_vector_type(4))) unsigned short u16x4;
typedef __attribute__((ext_vector_type(8))) unsigned short u16x8;
typedef __attribute__((ext_vector_type(8))) __bf16 bf16x8;
typedef __attribute__((ext_vector_type(4))) float f32x4;

__device__ __forceinline__ u16 f2bf(float f) {
  union { float f; unsigned int u; } v; v.f = f;
  unsigned int u = v.u;
  unsigned int r = (u + 0x7FFFu + ((u >> 16) & 1u)) >> 16;  // RNE
  return (u16)r;
}
__device__ __forceinline__ float bf2f(u16 b) {
  union { unsigned int u; float f; } v; v.u = ((unsigned int)b) << 16;
  return v.f;
}

__device__ __forceinline__ f32x4 mfma16(u16x8 a, u16x8 b, f32x4 c) {
  return __builtin_amdgcn_mfma_f32_16x16x32_bf16(
      __builtin_bit_cast(bf16x8, a), __builtin_bit_cast(bf16x8, b), c, 0, 0, 0);
}

// ---------------------------------------------------------------------------
// Kernel 1: cast inputs to bf16; transpose weights to (N x K) bf16.
// ---------------------------------------------------------------------------
__global__ __launch_bounds__(256) void cast_kernel(
    const float* __restrict__ q, const float* __restrict__ kv,
    const float* __restrict__ Wq, const float* __restrict__ Wk,
    const float* __restrict__ Wv,
    u16* __restrict__ qb, u16* __restrict__ kvb,
    u16* __restrict__ wqt, u16* __restrict__ wkt, u16* __restrict__ wvt) {
  int i = blockIdx.x * 256 + threadIdx.x;
  const int NVEC = (MROWS * D_) / 4;  // 524288 float4 casts
  if (i < NVEC) {
    float4 a = ((const float4*)q)[i];
    float4 b = ((const float4*)kv)[i];
    u16x4 ua = { f2bf(a.x), f2bf(a.y), f2bf(a.z), f2bf(a.w) };
    u16x4 ub = { f2bf(b.x), f2bf(b.y), f2bf(b.z), f2bf(b.w) };
    ((u16x4*)qb)[i]  = ua;
    ((u16x4*)kvb)[i] = ub;
  } else {
    int t = i - NVEC;            // 0 .. 3*512*512-1
    if (t < 3 * D_ * D_) {
      int w = t >> 18;           // which weight
      int r = t & (D_ * D_ - 1); // output index: n*512 + k
      int n = r >> 9, k = r & 511;
      const float* W = (w == 0) ? Wq : (w == 1) ? Wk : Wv;
      u16* WT = (w == 0) ? wqt : (w == 1) ? wkt : wvt;
      WT[r] = f2bf(W[k * D_ + n]);  // WT[n][k] = W[k][n]
    }
  }
}

// ---------------------------------------------------------------------------
// Kernel 2: fused QKV GEMM. Out(M x 512) = A(M x 512) * W + bias for the
// three projections in one launch. Block tile 64x128, 4 waves in 2x2 (each
// wave 32x64 = 2x4 MFMA fragments). 2-deep register prefetch on K.
// grid = (MROWS/64, 12): blockIdx.y 0-3 -> Q cols, 4-7 -> K, 8-11 -> V.
// ---------------------------------------------------------------------------
__global__ __launch_bounds__(256, 3) void gemm_qkv(
    const u16* __restrict__ qb, const u16* __restrict__ kvb,
    const u16* __restrict__ wqt, const u16* __restrict__ wkt,
    const u16* __restrict__ wvt,
    const float* __restrict__ bq, const float* __restrict__ bk,
    const float* __restrict__ bv,
    u16* __restrict__ Qp, u16* __restrict__ Kp, u16* __restrict__ Vp) {
  int lane = threadIdx.x & 63, w = threadIdx.x >> 6;
  int wr = w >> 1, wc = w & 1;
  int cl = lane & 15, g = lane >> 4;
  int cb = blockIdx.y;
  int which = cb >> 2;
  int row0 = blockIdx.x * 64, col0 = (cb & 3) * 128;

  const u16* A   = (which == 0) ? qb : kvb;
  const u16* WT  = (which == 0) ? wqt : (which == 1) ? wkt : wvt;
  const float* bias = (which == 0) ? bq : (which == 1) ? bk : bv;
  u16* Out = (which == 0) ? Qp : (which == 1) ? Kp : Vp;

  f32x4 acc[2][4] = {};
  const u16* Abase = A  + (size_t)(row0 + wr * 32 + cl) * D_ + g * 8;
  const u16* Bbase = WT + (size_t)(col0 + wc * 64 + cl) * D_ + g * 8;

  u16x8 afA[2], bfA[4], afB[2], bfB[4];
#pragma unroll
  for (int i = 0; i < 2; ++i) afA[i] = *(const u16x8*)(Abase + (size_t)i * 16 * D_);
#pragma unroll
  for (int j = 0; j < 4; ++j) bfA[j] = *(const u16x8*)(Bbase + (size_t)j * 16 * D_);

#pragma unroll
  for (int kk = 0; kk < 16; ++kk) {
    const u16x8* ca = (kk & 1) ? afB : afA;
    const u16x8* cw = (kk & 1) ? bfB : bfA;
    u16x8* na = (kk & 1) ? afA : afB;
    u16x8* nw = (kk & 1) ? bfA : bfB;
    if (kk < 15) {
      int k0 = kk * 32 + 32;
#pragma unroll
      for (int i = 0; i < 2; ++i) na[i] = *(const u16x8*)(Abase + (size_t)i * 16 * D_ + k0);
#pragma unroll
      for (int j = 0; j < 4; ++j) nw[j] = *(const u16x8*)(Bbase + (size_t)j * 16 * D_ + k0);
    }
#pragma unroll
    for (int i = 0; i < 2; ++i)
#pragma unroll
      for (int j = 0; j < 4; ++j)
        acc[i][j] = mfma16(ca[i], cw[j], acc[i][j]);
  }

  // Epilogue: C/D layout col = lane&15, row = (lane>>4)*4 + reg
#pragma unroll
  for (int j = 0; j < 4; ++j) {
    int col = col0 + wc * 64 + j * 16 + cl;
    float bv2 = bias[col];
#pragma unroll
    for (int i = 0; i < 2; ++i) {
      int rowb = row0 + wr * 32 + i * 16 + g * 4;
#pragma unroll
      for (int r = 0; r < 4; ++r)
        Out[(size_t)(rowb + r) * D_ + col] = f2bf(acc[i][j][r] + bv2);
    }
  }
}

// ---------------------------------------------------------------------------
// Kernel 3: split-KV flash attention per (b, h, split). Q-tile = 64 rows /
// block (4 waves x 16 rows), each block covers 512 keys. Writes unnormalized
// partial O (bf16) and per-row (m, l) (f32). Masked (query-half) keys are
// skipped entirely: expf(-1e4) == 0 in f32, softmax denominator unchanged.
// ---------------------------------------------------------------------------
__global__ __launch_bounds__(256, 8) void attn_kernel(
    const u16* __restrict__ Q, const u16* __restrict__ K,
    const u16* __restrict__ V, u16* __restrict__ opart,
    float* __restrict__ ml) {
  __shared__ u16 Vt[64][66];  // V transposed: [hd][key]; stride 132B (odd dw)
  __shared__ u16 Pl[64][66];  // P: [q_row_in_tile][key]

  int lane = threadIdx.x & 63, w = threadIdx.x >> 6;
  int cl = lane & 15, g = lane >> 4;
  int q0 = blockIdx.x * 64;
  int s  = blockIdx.y;                 // KV split
  int bh = blockIdx.z;                 // b*8 + h
  int b = bh >> 3, h = bh & 7;

  // Hoist Q fragments (wave w owns q-rows q0 + w*16 .. +15)
  const u16* Qb = Q + ((size_t)(b * NQ + q0 + w * 16 + cl)) * D_ + h * HD + g * 8;
  u16x8 qf0 = *(const u16x8*)Qb;
  u16x8 qf1 = *(const u16x8*)(Qb + 32);

  f32x4 o[4] = {};
  float m[4], lsum[4];
#pragma unroll
  for (int r = 0; r < 4; ++r) { m[r] = -1e30f; lsum[r] = 0.f; }

  const u16* Kb = K + (size_t)b * NKV * D_ + h * HD;
  const u16* Vb = V + (size_t)b * NKV * D_ + h * HD;

  for (int t = 0; t < SKEYS / 64; ++t) {
    int k0 = s * SKEYS + t * 64;
    __syncthreads();  // previous PV reads of Vt done before overwrite
    for (int s2 = threadIdx.x; s2 < 512; s2 += 256) {
      int key = s2 >> 3, hb = s2 & 7;
      u16x8 vv = *(const u16x8*)(Vb + (size_t)(k0 + key) * D_ + hb * 8);
#pragma unroll
      for (int e = 0; e < 8; ++e) Vt[hb * 8 + e][key] = vv[e];
    }
    __syncthreads();

    // S = Q K^T
    f32x4 sa[4] = {};
    const u16* Kt = Kb + (size_t)(k0 + cl) * D_ + g * 8;
#pragma unroll
    for (int kk = 0; kk < 2; ++kk) {
      u16x8 qf = kk ? qf1 : qf0;
#pragma unroll
      for (int j = 0; j < 4; ++j) {
        u16x8 kf = *(const u16x8*)(Kt + (size_t)j * 16 * D_ + kk * 32);
        sa[j] = mfma16(qf, kf, sa[j]);
      }
    }
#pragma unroll
    for (int j = 0; j < 4; ++j)
#pragma unroll
      for (int r = 0; r < 4; ++r) sa[j][r] *= 0.125f;  // 1/sqrt(HD)

    // Online softmax (reduction over the 16 lanes sharing g)
    float p[4][4], al[4];
#pragma unroll
    for (int r = 0; r < 4; ++r) {
      float mx = fmaxf(fmaxf(sa[0][r], sa[1][r]), fmaxf(sa[2][r], sa[3][r]));
#pragma unroll
      for (int d = 1; d < 16; d <<= 1) mx = fmaxf(mx, __shfl_xor(mx, d, 64));
      float mn = fmaxf(m[r], mx);
      al[r] = __expf(m[r] - mn);
      float sum = 0.f;
#pragma unroll
      for (int j = 0; j < 4; ++j) { p[j][r] = __expf(sa[j][r] - mn); sum += p[j][r]; }
#pragma unroll
      for (int d = 1; d < 16; d <<= 1) sum += __shfl_xor(sum, d, 64);
      lsum[r] = lsum[r] * al[r] + sum;
      m[r] = mn;
    }
#pragma unroll
    for (int j = 0; j < 4; ++j)
#pragma unroll
      for (int r = 0; r < 4; ++r) o[j][r] *= al[r];

    // P -> LDS (wave-local rows; DS ops within a wave are ordered)
#pragma unroll
    for (int j = 0; j < 4; ++j)
#pragma unroll
      for (int r = 0; r < 4; ++r)
        Pl[w * 16 + g * 4 + r][j * 16 + cl] = f2bf(p[j][r]);

    // O += P * V
#pragma unroll
    for (int kk = 0; kk < 2; ++kk) {
      u16x8 pa = *(const u16x8*)&Pl[w * 16 + cl][kk * 32 + g * 8];
#pragma unroll
      for (int j = 0; j < 4; ++j) {
        u16x8 vb2 = *(const u16x8*)&Vt[j * 16 + cl][kk * 32 + g * 8];
        o[j] = mfma16(pa, vb2, o[j]);
      }
    }
  }

  // Write partials: opart[(bh*NSPLIT+s)][row][hd] bf16, ml[(bh*NSPLIT+s)][row]{m,l}
  size_t pbase = ((size_t)(bh * NSPLIT + s) * NQ) * HD;
#pragma unroll
  for (int j = 0; j < 4; ++j)
#pragma unroll
    for (int r = 0; r < 4; ++r)
      opart[pbase + (size_t)(q0 + w * 16 + g * 4 + r) * HD + j * 16 + cl] = f2bf(o[j][r]);
  if (cl == 0) {
    size_t mlbase = ((size_t)(bh * NSPLIT + s) * NQ + q0 + w * 16 + g * 4) * 2;
#pragma unroll
    for (int r = 0; r < 4; ++r) {
      ml[mlbase + r * 2 + 0] = m[r];
      ml[mlbase + r * 2 + 1] = lsum[r];
    }
  }
}

// ---------------------------------------------------------------------------
// Kernel 4: combine split-KV partials + residual + LayerNorm, fused.
// One wave per row of 512. Lane covers global cols lane*8..lane*8+7, which
// lie inside head h = lane>>3.
// ---------------------------------------------------------------------------
__global__ __launch_bounds__(64) void combine_ln_kernel(
    const float* __restrict__ query, const u16* __restrict__ opart,
    const float* __restrict__ ml,
    const float* __restrict__ gamma, const float* __restrict__ beta,
    float* __restrict__ out) {
  int row = blockIdx.x;   // b*NQ + q
  int lane = threadIdx.x;
  int b = row >> 11, q = row & (NQ - 1);
  int h = lane >> 3;

  // Per-head combine factors
  float ms[NSPLIT], ls[NSPLIT];
  float mmax = -1e30f;
#pragma unroll
  for (int s = 0; s < NSPLIT; ++s) {
    size_t mi = ((size_t)((b * H_ + h) * NSPLIT + s) * NQ + q) * 2;
    ms[s] = ml[mi];
    ls[s] = ml[mi + 1];
    mmax = fmaxf(mmax, ms[s]);
  }
  float lt = 0.f;
#pragma unroll
  for (int s = 0; s < NSPLIT; ++s) lt += ls[s] * __expf(ms[s] - mmax);
  float inv = 1.f / lt;

  size_t base = (size_t)row * D_;
  const float4* q4 = (const float4*)(query + base);
  float4 a0 = q4[lane * 2], a1 = q4[lane * 2 + 1];
  float x[8] = { a0.x, a0.y, a0.z, a0.w, a1.x, a1.y, a1.z, a1.w };

#pragma unroll
  for (int s = 0; s < NSPLIT; ++s) {
    size_t oi = ((size_t)((b * H_ + h) * NSPLIT + s) * NQ + q) * HD + (lane & 7) * 8;
    u16x8 ov = *(const u16x8*)(opart + oi);
    float sc = __expf(ms[s] - mmax) * inv;
#pragma unroll
    for (int e = 0; e < 8; ++e) x[e] += bf2f(ov[e]) * sc;
  }

  float sum = 0.f, sq = 0.f;
#pragma unroll
  for (int e = 0; e < 8; ++e) { sum += x[e]; sq += x[e] * x[e]; }
#pragma unroll
  for (int d = 1; d < 64; d <<= 1) {
    sum += __shfl_xor(sum, d, 64);
    sq  += __shfl_xor(sq,  d, 64);
  }
  float mean = sum * (1.f / D_);
  float var  = sq * (1.f / D_) - mean * mean;
  float rstd = rsqrtf(var + 1e-5f);

  const float4* g4  = (const float4*)gamma;
  const float4* be4 = (const float4*)beta;
  float4 g0 = g4[lane * 2], g1 = g4[lane * 2 + 1];
  float4 e0 = be4[lane * 2], e1 = be4[lane * 2 + 1];
  float4 o0, o1;
  o0.x = (x[0] - mean) * rstd * g0.x + e0.x;
  o0.y = (x[1] - mean) * rstd * g0.y + e0.y;
  o0.z = (x[2] - mean) * rstd * g0.z + e0.z;
  o0.w = (x[3] - mean) * rstd * g0.w + e0.w;
  o1.x = (x[4] - mean) * rstd * g1.x + e1.x;
  o1.y = (x[5] - mean) * rstd * g1.y + e1.y;
  o1.z = (x[6] - mean) * rstd * g1.z + e1.z;
  o1.w = (x[7] - mean) * rstd * g1.w + e1.w;
  ((float4*)(out + base))[lane * 2]     = o0;
  ((float4*)(out + base))[lane * 2 + 1] = o1;
}

// ---------------------------------------------------------------------------
// Workspace layout (bytes). Cast buffers are dead once the GEMMs finish, so
// the attention partials overlay them:
//   0          Qp    : Q proj bf16        4 MB
//   4194304    Kp    : K proj bf16        4 MB
//   8388608    Vp    : V proj bf16        4 MB
//   12582912   opart : bf16 partial O     16 MB   (overlays qb/kvb/w*t)
//   29360128   ml    : f32 (m,l)          1 MB
//   -- overlay (pre-attention only) --
//   12582912   qb    : query bf16         4 MB
//   16777216   kvb   : key_value bf16     4 MB
//   20971520   wqt/wkt/wvt bf16           1.5 MB
//   total 30,408,704 bytes
// ---------------------------------------------------------------------------
extern "C" void kernel_launch(void* const* d_in, const int* in_sizes, int n_in,
                              void* d_out, int out_size, void* d_ws, size_t ws_size,
                              hipStream_t stream) {
  const float* query     = (const float*)d_in[0];
  const float* key_value = (const float*)d_in[1];
  const float* Wq = (const float*)d_in[2];
  const float* bq = (const float*)d_in[3];
  const float* Wk = (const float*)d_in[4];
  const float* bk = (const float*)d_in[5];
  const float* Wv = (const float*)d_in[6];
  const float* bv = (const float*)d_in[7];
  const float* gamma = (const float*)d_in[8];
  const float* beta  = (const float*)d_in[9];
  float* out = (float*)d_out;

  char* ws = (char*)d_ws;
  u16* Qp    = (u16*)(ws + 0);
  u16* Kp    = (u16*)(ws + 4194304);
  u16* Vp    = (u16*)(ws + 8388608);
  u16* opart = (u16*)(ws + 12582912);
  float* ml  = (float*)(ws + 29360128);
  u16* qb    = (u16*)(ws + 12582912);   // overlay, dead after gemm_qkv
  u16* kvb   = (u16*)(ws + 16777216);
  u16* wqt   = (u16*)(ws + 20971520);
  u16* wkt   = (u16*)(ws + 21495808);
  u16* wvt   = (u16*)(ws + 22020096);

  cast_kernel<<<5120, 256, 0, stream>>>(query, key_value, Wq, Wk, Wv,
                                        qb, kvb, wqt, wkt, wvt);
  dim3 gg(MROWS / 64, 12);
  gemm_qkv<<<gg, 256, 0, stream>>>(qb, kvb, wqt, wkt, wvt, bq, bk, bv,
                                   Qp, Kp, Vp);
  dim3 ga(NQ / 64, NSPLIT, H_ * B_);
  attn_kernel<<<ga, 256, 0, stream>>>(Qp, Kp, Vp, opart, ml);
  combine_ln_kernel<<<MROWS, 64, 0, stream>>>(query, opart, ml, gamma, beta, out);
}